// Round 2
// baseline (69.749 us; speedup 1.0000x reference)
//
#include <hip/hip_runtime.h>

#define Bx 16
#define Cx 64
#define Lx 512
#define Dx 768
#define NPx 68   // int((512+16)/8 + 2)
#define PER 7

// ---------------- Kernel A: m[b,l] = mean_c(x) / sqrt(var_c(x, ddof=1)) ----
__global__ void mean_var_kernel(const float* __restrict__ x,
                                float* __restrict__ m) {
    int idx = blockIdx.x * blockDim.x + threadIdx.x;  // b*Lx + l
    if (idx >= Bx * Lx) return;
    int b = idx / Lx, l = idx - b * Lx;
    const float* xp = x + (size_t)b * Cx * Lx + l;
    float s = 0.f, ss = 0.f;
#pragma unroll 8
    for (int c = 0; c < Cx; ++c) {
        float v = xp[(size_t)c * Lx];
        s += v;
        ss += v * v;
    }
    float mean = s / (float)Cx;
    float var = (ss - s * s / (float)Cx) / (float)(Cx - 1);
    m[idx] = mean * rsqrtf(var);
}

// ---------------- Kernel B: per-(b,c) decompose + projections ----
// Writes p[768] into out[bc][slot 0][:]; broadcast_kernel fills slots 1..67.
__global__ __launch_bounds__(256) void token_kernel(
    const float* __restrict__ x, const float* __restrict__ gamma,
    const float* __restrict__ beta, const float* __restrict__ m,
    const float* __restrict__ w_t, const float* __restrict__ b_t,
    const float* __restrict__ w_s, const float* __restrict__ b_s,
    const float* __restrict__ w_r, const float* __restrict__ b_r,
    const float* __restrict__ w_g, const float* __restrict__ b_g,
    float* __restrict__ out) {
    __shared__ __align__(16) float s_xt[Lx];
    __shared__ __align__(16) float s_tr[Lx];
    __shared__ __align__(16) float s_se[Lx];
    __shared__ __align__(16) float s_res[Lx];
    __shared__ float s_ph[PER];
    __shared__ __align__(16) float s_cat[48];

    const int bc = blockIdx.x;  // b*Cx + c
    const int b = bc / Cx;
    const int tid = threadIdx.x;

    const float* xp = x + (size_t)bc * Lx;
    const float* gp = gamma + (size_t)bc * Lx;
    const float* bp = beta + (size_t)bc * Lx;
    const float* mp = m + (size_t)b * Lx;

    // 1. xt = gamma*(x - m) + beta
    for (int l = tid; l < Lx; l += 256)
        s_xt[l] = gp[l] * (xp[l] - mp[l]) + bp[l];
    __syncthreads();

    // 2. trend = centered 7-pt MA, zero at edges (l in [3, Lx-4] valid)
    for (int l = tid; l < Lx; l += 256) {
        float t = 0.f;
        if (l >= 3 && l <= Lx - 4) {
#pragma unroll
            for (int k = -3; k <= 3; ++k) t += s_xt[l + k];
            t *= (1.f / 7.f);
        }
        s_tr[l] = t;
    }
    __syncthreads();

    // 3. per-phase averages of detrended interior
    if (tid < PER) {
        int p = tid;
        int l0 = p + 7 * ((3 - p + 6) / 7);  // smallest l>=3 with l%7==p
        float sum = 0.f;
        int cnt = 0;
        for (int l = l0; l <= Lx - 4; l += 7) {
            sum += s_xt[l] - s_tr[l];
            ++cnt;
        }
        s_ph[p] = sum / (float)cnt;
    }
    __syncthreads();
    if (tid == 0) {
        float mn = 0.f;
#pragma unroll
        for (int p = 0; p < PER; ++p) mn += s_ph[p];
        mn *= (1.f / 7.f);
#pragma unroll
        for (int p = 0; p < PER; ++p) s_ph[p] -= mn;
    }
    __syncthreads();

    // 4. seasonal (all l) + resid (interior only)
    for (int l = tid; l < Lx; l += 256) {
        float se = s_ph[l % PER];
        s_se[l] = se;
        s_res[l] = (l >= 3 && l <= Lx - 4) ? (s_xt[l] - s_tr[l] - se) : 0.f;
    }
    __syncthreads();

    // 5. cat[48] = [trend@w_t.T+b_t, seasonal@w_s.T+b_s, resid@w_r.T+b_r]
    {
        int j = tid >> 2, q = tid & 3;  // 4 lanes per output, 48 outputs
        if (j < 48) {
            const float* stream;
            const float* w;
            const float* bias;
            int jj;
            if (j < 16) {
                stream = s_tr; w = w_t; bias = b_t; jj = j;
            } else if (j < 32) {
                stream = s_se; w = w_s; bias = b_s; jj = j - 16;
            } else {
                stream = s_res; w = w_r; bias = b_r; jj = j - 32;
            }
            const float4* wr =
                reinterpret_cast<const float4*>(w + (size_t)jj * Lx + q * 128);
            const float4* sp = reinterpret_cast<const float4*>(stream + q * 128);
            float acc = 0.f;
#pragma unroll
            for (int i = 0; i < 32; ++i) {
                float4 a = sp[i], wv = wr[i];
                acc += a.x * wv.x + a.y * wv.y + a.z * wv.z + a.w * wv.w;
            }
            acc += __shfl_xor(acc, 1);
            acc += __shfl_xor(acc, 2);
            if (q == 0) s_cat[j] = acc + bias[jj];
        }
    }
    __syncthreads();

    // 6. p[768] = cat @ w_g.T + b_g  -> write to out[bc][slot 0][:]
    float* outp = out + (size_t)bc * NPx * Dx;
    const float4* c4 = reinterpret_cast<const float4*>(s_cat);
    for (int d = tid; d < Dx; d += 256) {
        const float4* wg4 = reinterpret_cast<const float4*>(w_g + (size_t)d * 48);
        float acc = 0.f;
#pragma unroll
        for (int kk = 0; kk < 12; ++kk) {
            float4 w4 = wg4[kk], cc = c4[kk];
            acc += w4.x * cc.x + w4.y * cc.y + w4.z * cc.z + w4.w * cc.w;
        }
        outp[d] = acc + b_g[d];
    }
}

// ---------------- Kernel C: broadcast slot 0 -> slots 1..67 ----
// Thread (chunk, bc, d4): 1 float4 load of out[bc][0][d4], ~17 float4 stores.
__global__ __launch_bounds__(256) void broadcast_kernel(float* __restrict__ out) {
    int gid = blockIdx.x * 256 + threadIdx.x;  // 4 * 1024 * 192 = 786432
    int d4 = gid % 192;
    int tmp = gid / 192;
    int bc = tmp & 1023;
    int chunk = tmp >> 10;  // 0..3

    float4* row = reinterpret_cast<float4*>(out) + (size_t)bc * (NPx * 192);
    float4 v = row[d4];  // slot 0, coalesced across lanes

    int n0 = 1 + chunk * 17;
    int cnt = min(17, NPx - n0);  // 17,17,17,16
    float4* dst = row + (size_t)n0 * 192 + d4;
    for (int n = 0; n < cnt; ++n) dst[n * 192] = v;
}

extern "C" void kernel_launch(void* const* d_in, const int* in_sizes, int n_in,
                              void* d_out, int out_size, void* d_ws,
                              size_t ws_size, hipStream_t stream) {
    const float* data_x = (const float*)d_in[0];
    // d_in[1] = data_y (unused by the reference)
    const float* gamma = (const float*)d_in[2];
    const float* beta = (const float*)d_in[3];
    const float* w_t = (const float*)d_in[4];
    const float* b_t = (const float*)d_in[5];
    const float* w_s = (const float*)d_in[6];
    const float* b_s = (const float*)d_in[7];
    const float* w_r = (const float*)d_in[8];
    const float* b_r = (const float*)d_in[9];
    const float* w_g = (const float*)d_in[10];
    const float* b_g = (const float*)d_in[11];
    float* out = (float*)d_out;
    float* m = (float*)d_ws;  // B*L floats = 32 KB

    int nthreads_m = Bx * Lx;
    mean_var_kernel<<<(nthreads_m + 255) / 256, 256, 0, stream>>>(data_x, m);

    token_kernel<<<Bx * Cx, 256, 0, stream>>>(data_x, gamma, beta, m, w_t, b_t,
                                              w_s, b_s, w_r, b_r, w_g, b_g,
                                              out);

    broadcast_kernel<<<(4 * Bx * Cx * 192) / 256, 256, 0, stream>>>(out);
}

// Round 3
// 68.153 us; speedup vs baseline: 1.0234x; 1.0234x over previous
//
#include <hip/hip_runtime.h>

#define Bx 16
#define Cx 64
#define Lx 512
#define Dx 768
#define NPx 68   // int((512+16)/8 + 2)
#define PER 7

// One block per (b,c). Does everything: channel stats for m, RevIN affine,
// seasonal decompose, three Linear(512->16), Linear(48->768), and the
// 68-slot broadcast store. Single graph node, no inter-kernel drains.
__global__ __launch_bounds__(256) void fused_kernel(
    const float* __restrict__ x, const float* __restrict__ gamma,
    const float* __restrict__ beta,
    const float* __restrict__ w_t, const float* __restrict__ b_t,
    const float* __restrict__ w_s, const float* __restrict__ b_s,
    const float* __restrict__ w_r, const float* __restrict__ b_r,
    const float* __restrict__ w_g, const float* __restrict__ b_g,
    float* __restrict__ out) {
    __shared__ __align__(16) float s_m[Lx];
    __shared__ __align__(16) float s_xt[Lx];
    __shared__ __align__(16) float s_tr[Lx];
    __shared__ __align__(16) float s_det[Lx];
    __shared__ __align__(16) float s_se[Lx];
    __shared__ __align__(16) float s_res[Lx];
    __shared__ float s_ph[PER];
    __shared__ __align__(16) float s_cat[48];
    __shared__ __align__(16) float s_p[Dx];
    __shared__ __align__(16) float red_s[2][128][4];
    __shared__ __align__(16) float red_ss[2][128][4];

    const int bc = blockIdx.x;  // b*Cx + c
    const int b = bc >> 6;
    const int tid = threadIdx.x;

    // ---- prefetch this block's own row (hides HBM latency under stats) ----
    const float* xrow = x + (size_t)bc * Lx;
    const float* grow = gamma + (size_t)bc * Lx;
    const float* brow = beta + (size_t)bc * Lx;
    float xv0 = xrow[tid], xv1 = xrow[tid + 256];
    float gv0 = grow[tid], gv1 = grow[tid + 256];
    float bv0 = brow[tid], bv1 = brow[tid + 256];

    // ---- channel stats: m[l] = mean_c / sqrt(var_c (ddof=1)) over x[b] ----
    {
        int g = tid >> 7, j = tid & 127;  // 2 groups of 32 channels, 128 l4's
        const float* xb = x + (size_t)b * Cx * Lx + (size_t)g * 32 * Lx + 4 * j;
        float s0 = 0.f, s1 = 0.f, s2 = 0.f, s3 = 0.f;
        float q0 = 0.f, q1 = 0.f, q2 = 0.f, q3 = 0.f;
#pragma unroll 4
        for (int c = 0; c < 32; ++c) {
            float4 v = *reinterpret_cast<const float4*>(xb + (size_t)c * Lx);
            s0 += v.x; s1 += v.y; s2 += v.z; s3 += v.w;
            q0 += v.x * v.x; q1 += v.y * v.y; q2 += v.z * v.z; q3 += v.w * v.w;
        }
        red_s[g][j][0] = s0; red_s[g][j][1] = s1;
        red_s[g][j][2] = s2; red_s[g][j][3] = s3;
        red_ss[g][j][0] = q0; red_ss[g][j][1] = q1;
        red_ss[g][j][2] = q2; red_ss[g][j][3] = q3;
    }
    __syncthreads();
    if (tid < 128) {
#pragma unroll
        for (int k = 0; k < 4; ++k) {
            float s = red_s[0][tid][k] + red_s[1][tid][k];
            float q = red_ss[0][tid][k] + red_ss[1][tid][k];
            float mean = s * (1.f / (float)Cx);
            float var = (q - s * s * (1.f / (float)Cx)) * (1.f / (float)(Cx - 1));
            s_m[4 * tid + k] = mean * rsqrtf(var);
        }
    }
    __syncthreads();

    // ---- xt = gamma*(x - m) + beta ----
    s_xt[tid] = gv0 * (xv0 - s_m[tid]) + bv0;
    s_xt[tid + 256] = gv1 * (xv1 - s_m[tid + 256]) + bv1;
    __syncthreads();

    // ---- trend (7-pt centered MA) + det = xt - trend on interior ----
#pragma unroll
    for (int u = 0; u < 2; ++u) {
        int l = tid + u * 256;
        float t = 0.f, d = 0.f;
        if (l >= 3 && l <= Lx - 4) {
#pragma unroll
            for (int k = -3; k <= 3; ++k) t += s_xt[l + k];
            t *= (1.f / 7.f);
            d = s_xt[l] - t;
        }
        s_tr[l] = t;
        s_det[l] = d;
    }
    __syncthreads();

    // ---- per-phase averages: 7 phases x 32 lanes, shuffle-reduce ----
    if (tid < 224) {
        int p = tid >> 5, j = tid & 31;
        int l0 = p + 7 * ((3 - p + 6) / 7);      // first valid l of phase p
        int cnt = (Lx - 4 - l0) / 7 + 1;
        float sum = 0.f;
#pragma unroll
        for (int k = 0; k < 3; ++k) {
            int idx = j + 32 * k;
            if (idx < cnt) sum += s_det[l0 + 7 * idx];  // stride-7: bank-free
        }
#pragma unroll
        for (int off = 16; off >= 1; off >>= 1) sum += __shfl_xor(sum, off);
        if (j == 0) s_ph[p] = sum / (float)cnt;
    }
    __syncthreads();
    if (tid == 0) {
        float mn = 0.f;
#pragma unroll
        for (int p = 0; p < PER; ++p) mn += s_ph[p];
        mn *= (1.f / 7.f);
#pragma unroll
        for (int p = 0; p < PER; ++p) s_ph[p] -= mn;
    }
    __syncthreads();

    // ---- seasonal (all l) + resid (interior) ----
#pragma unroll
    for (int u = 0; u < 2; ++u) {
        int l = tid + u * 256;
        float se = s_ph[l % PER];
        s_se[l] = se;
        s_res[l] = (l >= 3 && l <= Lx - 4) ? (s_det[l] - se) : 0.f;
    }
    __syncthreads();

    // ---- cat[48]: three Linear(512->16); one wave per stream ----
    if (tid < 192) {
        int j = tid >> 2, q = tid & 3;
        const float* stream;
        const float* w;
        const float* bias;
        int jj;
        if (j < 16) {
            stream = s_tr; w = w_t; bias = b_t; jj = j;
        } else if (j < 32) {
            stream = s_se; w = w_s; bias = b_s; jj = j - 16;
        } else {
            stream = s_res; w = w_r; bias = b_r; jj = j - 32;
        }
        const float4* wr =
            reinterpret_cast<const float4*>(w + (size_t)jj * Lx + q * 128);
        const float4* sp = reinterpret_cast<const float4*>(stream + q * 128);
        float acc = 0.f;
#pragma unroll 8
        for (int i = 0; i < 32; ++i) {
            float4 a = sp[i], wv = wr[i];
            acc += a.x * wv.x + a.y * wv.y + a.z * wv.z + a.w * wv.w;
        }
        acc += __shfl_xor(acc, 1);
        acc += __shfl_xor(acc, 2);
        if (q == 0) s_cat[j] = acc + bias[jj];
    }
    __syncthreads();

    // ---- p[768] = cat @ w_g.T + b_g ----
    {
        const float4* c4 = reinterpret_cast<const float4*>(s_cat);
#pragma unroll
        for (int u = 0; u < 3; ++u) {
            int d = tid + u * 256;
            const float4* wg4 =
                reinterpret_cast<const float4*>(w_g + (size_t)d * 48);
            float acc = 0.f;
#pragma unroll
            for (int kk = 0; kk < 12; ++kk) {
                float4 w4 = wg4[kk], cc = c4[kk];
                acc += w4.x * cc.x + w4.y * cc.y + w4.z * cc.z + w4.w * cc.w;
            }
            s_p[d] = acc + b_g[d];
        }
    }
    __syncthreads();

    // ---- broadcast: 192 threads, register value, 68 coalesced f4 stores ----
    if (tid < 192) {
        float4 v = reinterpret_cast<const float4*>(s_p)[tid];
        float4* dst = reinterpret_cast<float4*>(out + (size_t)bc * NPx * Dx) + tid;
#pragma unroll
        for (int n = 0; n < NPx; ++n) dst[(size_t)n * 192] = v;
    }
}

extern "C" void kernel_launch(void* const* d_in, const int* in_sizes, int n_in,
                              void* d_out, int out_size, void* d_ws,
                              size_t ws_size, hipStream_t stream) {
    const float* data_x = (const float*)d_in[0];
    // d_in[1] = data_y (unused by the reference)
    const float* gamma = (const float*)d_in[2];
    const float* beta = (const float*)d_in[3];
    const float* w_t = (const float*)d_in[4];
    const float* b_t = (const float*)d_in[5];
    const float* w_s = (const float*)d_in[6];
    const float* b_s = (const float*)d_in[7];
    const float* w_r = (const float*)d_in[8];
    const float* b_r = (const float*)d_in[9];
    const float* w_g = (const float*)d_in[10];
    const float* b_g = (const float*)d_in[11];
    float* out = (float*)d_out;

    fused_kernel<<<Bx * Cx, 256, 0, stream>>>(data_x, gamma, beta, w_t, b_t,
                                              w_s, b_s, w_r, b_r, w_g, b_g,
                                              out);
}